// Round 3
// baseline (71.976 us; speedup 1.0000x reference)
//
#include <hip/hip_runtime.h>

// RegistrationRecall: out = (sqrt(mean_n(min_m ||src_n - tgt_m||)^2) < 0.1) ? 1 : 0
// N = M = 8192, D = 3, fp32.
//
// Each 64-lane wave owns S=2 source points (registers); lanes split the 8192
// targets, 8 targets per lane per iter via 6 float4 loads (96 contiguous
// B/lane). 16 pairs per 6 loads = ~224 VALU cycles of cover, and 4096 waves
// give 4 waves/SIMD of TLP on top. min-chain is exactly associative (compiler
// may fuse v_min3_f32); squared-distance arithmetic kept in the reference's
// exact direct-difference form.

#define N_SRC 8192
#define N_TGT 8192
#define S     2                          // sources per wave
#define BLOCK 256                        // 4 waves per block
#define SRC_PER_BLOCK (4 * S)            // 8
#define NBLOCKS (N_SRC / SRC_PER_BLOCK)  // 1024 blocks -> 4096 waves
#define TPL   8                          // targets per lane per iter
#define ITERS (N_TGT / (64 * TPL))       // 16

__global__ __launch_bounds__(BLOCK, 4) void knn_partial(const float* __restrict__ src,
                                                        const float* __restrict__ tgt,
                                                        float* __restrict__ partials) {
    const int tid  = threadIdx.x;
    const int lane = tid & 63;
    const int wave = tid >> 6;
    const int g    = blockIdx.x * 4 + wave;        // source-pair group id

    float sx[S], sy[S], sz[S];
    const float* sp = src + g * S * 3;
    #pragma unroll
    for (int i = 0; i < S; ++i) {
        sx[i] = sp[3 * i + 0];
        sy[i] = sp[3 * i + 1];
        sz[i] = sp[3 * i + 2];
    }

    float m[S];
    #pragma unroll
    for (int i = 0; i < S; ++i) m[i] = 1e30f;

    const float* tb = tgt + lane * (TPL * 3);      // 96 B per lane, contiguous

    #pragma unroll 2
    for (int it = 0; it < ITERS; ++it) {
        const float4 t0 = *(const float4*)(tb + 0);
        const float4 t1 = *(const float4*)(tb + 4);
        const float4 t2 = *(const float4*)(tb + 8);
        const float4 t3 = *(const float4*)(tb + 12);
        const float4 t4 = *(const float4*)(tb + 16);
        const float4 t5 = *(const float4*)(tb + 20);
        tb += 64 * TPL * 3;

        const float tx[TPL] = {t0.x, t0.w, t1.z, t2.y, t3.x, t3.w, t4.z, t5.y};
        const float ty[TPL] = {t0.y, t1.x, t1.w, t2.z, t3.y, t4.x, t4.w, t5.z};
        const float tz[TPL] = {t0.z, t1.y, t2.x, t2.w, t3.z, t4.y, t5.x, t5.w};

        #pragma unroll
        for (int j = 0; j < TPL; ++j) {
            #pragma unroll
            for (int i = 0; i < S; ++i) {
                const float dx = sx[i] - tx[j];
                const float dy = sy[i] - ty[j];
                const float dz = sz[i] - tz[j];
                const float d2 = dx * dx + dy * dy + dz * dz;
                m[i] = fminf(m[i], d2);
            }
        }
    }

    // butterfly min across the 64 lanes for each source
    #pragma unroll
    for (int off = 1; off < 64; off <<= 1) {
        #pragma unroll
        for (int i = 0; i < S; ++i)
            m[i] = fminf(m[i], __shfl_xor(m[i], off));
    }

    // replicate reference rounding: d = sqrt(min d2); accumulate d*d
    float c = 0.0f;
    #pragma unroll
    for (int i = 0; i < S; ++i) {
        const float d = sqrtf(m[i]);
        c += d * d;
    }

    __shared__ float wsum[BLOCK / 64];
    if (lane == 0) wsum[wave] = c;
    __syncthreads();
    if (tid == 0)
        partials[blockIdx.x] = wsum[0] + wsum[1] + wsum[2] + wsum[3];
}

__global__ __launch_bounds__(256) void knn_finalize(const float* __restrict__ partials,
                                                    float* __restrict__ out) {
    const int tid = threadIdx.x;
    float v = partials[tid] + partials[tid + 256]
            + partials[tid + 512] + partials[tid + 768];   // NBLOCKS = 1024

    #pragma unroll
    for (int off = 1; off < 64; off <<= 1)
        v += __shfl_xor(v, off);

    __shared__ float wsum[4];
    if ((tid & 63) == 0) wsum[tid >> 6] = v;
    __syncthreads();
    if (tid == 0) {
        const float total = wsum[0] + wsum[1] + wsum[2] + wsum[3];
        const float rmse = sqrtf(total / (float)N_SRC);
        out[0] = (rmse < 0.1f) ? 1.0f : 0.0f;
    }
}

extern "C" void kernel_launch(void* const* d_in, const int* in_sizes, int n_in,
                              void* d_out, int out_size, void* d_ws, size_t ws_size,
                              hipStream_t stream) {
    const float* src = (const float*)d_in[0];
    const float* tgt = (const float*)d_in[1];
    float* partials  = (float*)d_ws;     // NBLOCKS floats
    float* out       = (float*)d_out;

    knn_partial<<<NBLOCKS, BLOCK, 0, stream>>>(src, tgt, partials);
    knn_finalize<<<1, 256, 0, stream>>>(partials, out);
}

// Round 4
// 69.455 us; speedup vs baseline: 1.0363x; 1.0363x over previous
//
#include <hip/hip_runtime.h>

// RegistrationRecall: out = (sqrt(mean_n(min_m ||src_n - tgt_m||)^2) < 0.1) ? 1 : 0
// N = M = 8192, D = 3, fp32.
//
// The timed graph contains a ~40 us harness re-poison fill of d_ws (268 MB at
// ~6.8 TB/s) that saturates HBM/L2. So the pair loop is made cache-immune:
// each block stages targets into LDS (2 tiles x 4096 targets x 12 B = 48 KB),
// then computes entirely from LDS. Packed-xyz LDS reads (3x ds_read_b128,
// 48 B/lane) are bank-conflict-free: start banks (12*lane)%32 cover all 32
// banks exactly once per 8-lane phase. Per wave: 32 iters x 224 VALU cyc ->
// ~6 us compute floor at 2 waves/SIMD. min-chain stays in the reference's
// exact direct-difference arithmetic.

#define N_SRC 8192
#define N_TGT 8192
#define S     4                          // sources per wave
#define BLOCK 256                        // 4 waves per block
#define WAVES (BLOCK / 64)
#define SRC_PER_BLOCK (WAVES * S)        // 16
#define NBLOCKS (N_SRC / SRC_PER_BLOCK)  // 512
#define TILE  4096                       // targets per LDS tile (48 KB)
#define NTILES (N_TGT / TILE)            // 2
#define TPL   4                          // targets per lane per inner iter
#define IT_PER_TILE (TILE / (64 * TPL))  // 16

__global__ __launch_bounds__(BLOCK, 2) void knn_partial(const float* __restrict__ src,
                                                        const float* __restrict__ tgt,
                                                        float* __restrict__ partials) {
    __shared__ float tile[TILE * 3];     // 49152 B, packed xyz
    __shared__ float wsum[WAVES];

    const int tid  = threadIdx.x;
    const int lane = tid & 63;
    const int wave = tid >> 6;
    const int g    = blockIdx.x * WAVES + wave;    // source group id

    float sx[S], sy[S], sz[S], m[S];
    const float* sp = src + g * S * 3;
    #pragma unroll
    for (int i = 0; i < S; ++i) {
        sx[i] = sp[3 * i + 0];
        sy[i] = sp[3 * i + 1];
        sz[i] = sp[3 * i + 2];
        m[i]  = 1e30f;
    }

    for (int t = 0; t < NTILES; ++t) {
        // ---- stage 4096 targets (12288 floats = 3072 float4) into LDS ----
        const float4* gs = (const float4*)(tgt + t * TILE * 3);
        float4* ls = (float4*)tile;
        #pragma unroll
        for (int k = 0; k < (TILE * 3 / 4) / BLOCK; ++k)   // 12 float4/thread
            ls[tid + k * BLOCK] = gs[tid + k * BLOCK];
        __syncthreads();

        // ---- compute: each lane takes 4 consecutive targets per iter ----
        #pragma unroll 2
        for (int it = 0; it < IT_PER_TILE; ++it) {
            const float* tb = tile + (it * 256 + lane * TPL) * 3;
            const float4 t0 = *(const float4*)(tb + 0);
            const float4 t1 = *(const float4*)(tb + 4);
            const float4 t2 = *(const float4*)(tb + 8);

            const float tx[TPL] = {t0.x, t0.w, t1.z, t2.y};
            const float ty[TPL] = {t0.y, t1.x, t1.w, t2.z};
            const float tz[TPL] = {t0.z, t1.y, t2.x, t2.w};

            #pragma unroll
            for (int j = 0; j < TPL; ++j) {
                #pragma unroll
                for (int i = 0; i < S; ++i) {
                    const float dx = sx[i] - tx[j];
                    const float dy = sy[i] - ty[j];
                    const float dz = sz[i] - tz[j];
                    const float d2 = dx * dx + dy * dy + dz * dz;
                    m[i] = fminf(m[i], d2);
                }
            }
        }
        __syncthreads();
    }

    // butterfly min across the 64 lanes for each source
    #pragma unroll
    for (int off = 1; off < 64; off <<= 1) {
        #pragma unroll
        for (int i = 0; i < S; ++i)
            m[i] = fminf(m[i], __shfl_xor(m[i], off));
    }

    // replicate reference rounding: d = sqrt(min d2); accumulate d*d
    float c = 0.0f;
    #pragma unroll
    for (int i = 0; i < S; ++i) {
        const float d = sqrtf(m[i]);
        c += d * d;
    }

    if (lane == 0) wsum[wave] = c;
    __syncthreads();
    if (tid == 0)
        partials[blockIdx.x] = wsum[0] + wsum[1] + wsum[2] + wsum[3];
}

__global__ __launch_bounds__(256) void knn_finalize(const float* __restrict__ partials,
                                                    float* __restrict__ out) {
    const int tid = threadIdx.x;
    float v = partials[tid] + partials[tid + 256];   // NBLOCKS = 512

    #pragma unroll
    for (int off = 1; off < 64; off <<= 1)
        v += __shfl_xor(v, off);

    __shared__ float wsum[4];
    if ((tid & 63) == 0) wsum[tid >> 6] = v;
    __syncthreads();
    if (tid == 0) {
        const float total = wsum[0] + wsum[1] + wsum[2] + wsum[3];
        const float rmse = sqrtf(total / (float)N_SRC);
        out[0] = (rmse < 0.1f) ? 1.0f : 0.0f;
    }
}

extern "C" void kernel_launch(void* const* d_in, const int* in_sizes, int n_in,
                              void* d_out, int out_size, void* d_ws, size_t ws_size,
                              hipStream_t stream) {
    const float* src = (const float*)d_in[0];
    const float* tgt = (const float*)d_in[1];
    float* partials  = (float*)d_ws;     // NBLOCKS floats
    float* out       = (float*)d_out;

    knn_partial<<<NBLOCKS, BLOCK, 0, stream>>>(src, tgt, partials);
    knn_finalize<<<1, 256, 0, stream>>>(partials, out);
}

// Round 5
// 69.358 us; speedup vs baseline: 1.0377x; 1.0014x over previous
//
#include <hip/hip_runtime.h>
#include <stdint.h>

// RegistrationRecall: out = (sqrt(mean_n(min_m ||src_n - tgt_m||)^2) < 0.1) ? 1 : 0
// N = M = 8192, D = 3, fp32.
//
// 2-phase pipelined LDS version: double-buffered 2048-target tiles staged via
// __builtin_amdgcn_global_load_lds (16B, no VGPR round-trip), prefetch of tile
// t+1 issued BEFORE compute of tile t so the vmcnt(0) drain at the barrier is
// free. Each 64-lane wave owns S=4 sources in registers; lane reads 4 packed
// targets (3x ds_read_b128, 48 B) -> 16 pairs per 3 LDS reads, conflict-free
// (start banks 12*lane%32 cover all 32 banks per 8-lane phase). Exact
// direct-difference arithmetic preserved (rmse may sit near the 0.1 threshold).

#define N_SRC 8192
#define N_TGT 8192
#define S     4                          // sources per wave
#define BLOCK 256                        // 4 waves per block
#define WAVES (BLOCK / 64)
#define SRC_PER_BLOCK (WAVES * S)        // 16
#define NBLOCKS (N_SRC / SRC_PER_BLOCK)  // 512
#define TILE  2048                       // targets per LDS tile (24.6 KB)
#define NTILES (N_TGT / TILE)            // 4
#define TPL   4                          // targets per lane per inner iter
#define IT_PER_TILE (TILE / (64 * TPL))  // 8
#define F4_PER_TILE (TILE * 3 / 4)       // 1536 float4
#define F4_PER_THREAD (F4_PER_TILE / BLOCK) // 6

#define GL2LDS16(gp, lp)                                                     \
    __builtin_amdgcn_global_load_lds(                                        \
        (const __attribute__((address_space(1))) void*)(const void*)(gp),    \
        (__attribute__((address_space(3))) void*)(void*)(lp), 16, 0, 0)

__global__ __launch_bounds__(BLOCK, 2) void knn_partial(const float* __restrict__ src,
                                                        const float* __restrict__ tgt,
                                                        float* __restrict__ partials) {
    __shared__ float buf[2][TILE * 3];   // 2 x 24576 B
    __shared__ float wsum[WAVES];

    const int tid  = threadIdx.x;
    const int lane = tid & 63;
    const int wave = tid >> 6;
    const int g    = blockIdx.x * WAVES + wave;    // source group id

    float sx[S], sy[S], sz[S], m[S];
    const float* sp = src + g * S * 3;
    #pragma unroll
    for (int i = 0; i < S; ++i) {
        sx[i] = sp[3 * i + 0];
        sy[i] = sp[3 * i + 1];
        sz[i] = sp[3 * i + 2];
        m[i]  = 1e30f;
    }

    // ---- stage tile 0 ----
    {
        const float4* gs = (const float4*)tgt;
        float4* ls = (float4*)buf[0];
        #pragma unroll
        for (int k = 0; k < F4_PER_THREAD; ++k) {
            const int idx = k * BLOCK + tid;
            GL2LDS16(gs + idx, ls + idx);
        }
    }
    __syncthreads();                      // drains vmcnt(0): tile 0 ready

    for (int t = 0; t < NTILES; ++t) {
        // ---- issue prefetch of tile t+1 into the other buffer ----
        if (t + 1 < NTILES) {
            const float4* gs = (const float4*)(tgt + (t + 1) * TILE * 3);
            float4* ls = (float4*)buf[(t + 1) & 1];
            #pragma unroll
            for (int k = 0; k < F4_PER_THREAD; ++k) {
                const int idx = k * BLOCK + tid;
                GL2LDS16(gs + idx, ls + idx);
            }
        }

        // ---- compute from buf[t&1] (ds_read only, no vmcnt dependence) ----
        const float* tile = buf[t & 1];
        #pragma unroll 2
        for (int it = 0; it < IT_PER_TILE; ++it) {
            const float* tb = tile + (it * 256 + lane * TPL) * 3;
            const float4 t0 = *(const float4*)(tb + 0);
            const float4 t1 = *(const float4*)(tb + 4);
            const float4 t2 = *(const float4*)(tb + 8);

            const float tx[TPL] = {t0.x, t0.w, t1.z, t2.y};
            const float ty[TPL] = {t0.y, t1.x, t1.w, t2.z};
            const float tz[TPL] = {t0.z, t1.y, t2.x, t2.w};

            #pragma unroll
            for (int j = 0; j < TPL; ++j) {
                #pragma unroll
                for (int i = 0; i < S; ++i) {
                    const float dx = sx[i] - tx[j];
                    const float dy = sy[i] - ty[j];
                    const float dz = sz[i] - tz[j];
                    const float d2 = dx * dx + dy * dy + dz * dz;
                    m[i] = fminf(m[i], d2);
                }
            }
        }
        __syncthreads();                  // next tile landed + everyone done reading
    }

    // butterfly min across the 64 lanes for each source
    #pragma unroll
    for (int off = 1; off < 64; off <<= 1) {
        #pragma unroll
        for (int i = 0; i < S; ++i)
            m[i] = fminf(m[i], __shfl_xor(m[i], off));
    }

    // replicate reference rounding: d = sqrt(min d2); accumulate d*d
    float c = 0.0f;
    #pragma unroll
    for (int i = 0; i < S; ++i) {
        const float d = sqrtf(m[i]);
        c += d * d;
    }

    if (lane == 0) wsum[wave] = c;
    __syncthreads();
    if (tid == 0)
        partials[blockIdx.x] = wsum[0] + wsum[1] + wsum[2] + wsum[3];
}

__global__ __launch_bounds__(256) void knn_finalize(const float* __restrict__ partials,
                                                    float* __restrict__ out) {
    const int tid = threadIdx.x;
    float v = partials[tid] + partials[tid + 256];   // NBLOCKS = 512

    #pragma unroll
    for (int off = 1; off < 64; off <<= 1)
        v += __shfl_xor(v, off);

    __shared__ float wsum[4];
    if ((tid & 63) == 0) wsum[tid >> 6] = v;
    __syncthreads();
    if (tid == 0) {
        const float total = wsum[0] + wsum[1] + wsum[2] + wsum[3];
        const float rmse = sqrtf(total / (float)N_SRC);
        out[0] = (rmse < 0.1f) ? 1.0f : 0.0f;
    }
}

extern "C" void kernel_launch(void* const* d_in, const int* in_sizes, int n_in,
                              void* d_out, int out_size, void* d_ws, size_t ws_size,
                              hipStream_t stream) {
    const float* src = (const float*)d_in[0];
    const float* tgt = (const float*)d_in[1];
    float* partials  = (float*)d_ws;     // NBLOCKS floats
    float* out       = (float*)d_out;

    knn_partial<<<NBLOCKS, BLOCK, 0, stream>>>(src, tgt, partials);
    knn_finalize<<<1, 256, 0, stream>>>(partials, out);
}